// Round 6
// baseline (193.316 us; speedup 1.0000x reference)
//
#include <hip/hip_runtime.h>
#include <hip/hip_bf16.h>

// Output[b,0,i] = S[b] for all i, where
//   S[b] = sum_j (row[b,j] + b_row) * (col[b,j] + b_col)
//   col[b,i] = sum_j x[b,i,j] * w_col[j]   (weighted row-dot)
//   row[b,j] = sum_i x[b,i,j] * w_row[i]   (weighted column-sum)
//
// R6 = R3 structure (best known: 109 us) + __launch_bounds__(256,4) ONLY.
// No software pipeline (that + the cap together spilled in R5).
// Cap 128 VGPR -> 4 waves/SIMD resident (was 3) for more memory-level
// parallelism; register demand ~85 VGPR fits without spill.

#define K 1024
#define NB 128

typedef float f32x4 __attribute__((ext_vector_type(4)));

__global__ __launch_bounds__(256, 4) void
rowcol_kernel(const float* __restrict__ x,
              const float* __restrict__ w_col,
              const float* __restrict__ w_row,
              float* __restrict__ col_ws,     // [NB][K] raw (no bias)
              float* __restrict__ rowpart)    // [NB*16][K] per-block partials
{
    const int bid  = blockIdx.x;
    const int b    = bid >> 4;
    const int rb   = bid & 15;
    const int row0 = rb * 64;
    const int tid  = threadIdx.x;
    const int wave = tid >> 6;
    const int lane = tid & 63;

    const float* xb = x + (size_t)b * K * K;

    // Wave-uniform row base in SGPR so w_row[] reads scalarize to s_load.
    const int rbu = __builtin_amdgcn_readfirstlane(row0 + wave * 16);

    // Register-cache this lane's w_col fragment (reused by all 16 rows)
    f32x4 wc[4];
#pragma unroll
    for (int jt = 0; jt < 4; ++jt)
        wc[jt] = *reinterpret_cast<const f32x4*>(w_col + jt * 256 + lane * 4);

    // Per-lane column partials for row[b,j] (this wave's 16 rows)
    f32x4 p[4];
#pragma unroll
    for (int jt = 0; jt < 4; ++jt) p[jt] = (f32x4){0.f, 0.f, 0.f, 0.f};

    float cacc[16];

#pragma unroll
    for (int k = 0; k < 16; ++k) {
        const float wr = w_row[rbu + k];            // s_load, wave-uniform
        const float* xr = xb + (size_t)(rbu + k) * K;
        f32x4 xv0 = __builtin_nontemporal_load(reinterpret_cast<const f32x4*>(xr +   0 + lane * 4));
        f32x4 xv1 = __builtin_nontemporal_load(reinterpret_cast<const f32x4*>(xr + 256 + lane * 4));
        f32x4 xv2 = __builtin_nontemporal_load(reinterpret_cast<const f32x4*>(xr + 512 + lane * 4));
        f32x4 xv3 = __builtin_nontemporal_load(reinterpret_cast<const f32x4*>(xr + 768 + lane * 4));
        f32x4 c4;
        c4  = xv0 * wc[0];
        c4 += xv1 * wc[1];
        c4 += xv2 * wc[2];
        c4 += xv3 * wc[3];
        p[0] += xv0 * wr;
        p[1] += xv1 * wr;
        p[2] += xv2 * wr;
        p[3] += xv3 * wr;
        cacc[k] = (c4.x + c4.y) + (c4.z + c4.w);
    }

    // Multiplexed butterfly: 16 row-dots reduced across 64 lanes.
#pragma unroll
    for (int lvl = 0; lvl < 4; ++lvl) {
        const int s = 1 << lvl;
        const int n = 16 >> (lvl + 1);
#pragma unroll
        for (int m = 0; m < n; ++m) {
            float a  = cacc[2 * m]     + __shfl_xor(cacc[2 * m],     s);
            float bb = cacc[2 * m + 1] + __shfl_xor(cacc[2 * m + 1], s);
            cacc[m] = (lane & s) ? bb : a;
        }
    }
    float r = cacc[0];
    r += __shfl_xor(r, 16);
    r += __shfl_xor(r, 32);
    if (lane < 16) col_ws[b * K + rbu + lane] = r;   // one coalesced 64B store

    // Combine the 4 waves' column partials in LDS, write this block's partial
    __shared__ float rp[4][K];   // 16 KiB
#pragma unroll
    for (int jt = 0; jt < 4; ++jt)
        *reinterpret_cast<f32x4*>(&rp[wave][jt * 256 + lane * 4]) = p[jt];
    __syncthreads();

    const int j0 = tid * 4;   // thread tid owns columns j0..j0+3
    f32x4 s0 = *reinterpret_cast<const f32x4*>(&rp[0][j0]);
    f32x4 s1 = *reinterpret_cast<const f32x4*>(&rp[1][j0]);
    f32x4 s2 = *reinterpret_cast<const f32x4*>(&rp[2][j0]);
    f32x4 s3 = *reinterpret_cast<const f32x4*>(&rp[3][j0]);
    f32x4 s = (s0 + s1) + (s2 + s3);
    *reinterpret_cast<f32x4*>(&rowpart[(size_t)bid * K + j0]) = s;
}

__global__ __launch_bounds__(256) void
finalize_kernel(const float* __restrict__ col_ws,
                const float* __restrict__ rowpart,
                const float* __restrict__ b_col_p,
                const float* __restrict__ b_row_p,
                float* __restrict__ out)
{
    const int b    = blockIdx.x;
    const int tid  = threadIdx.x;
    const int wave = tid >> 6;
    const int lane = tid & 63;
    const float bc = b_col_p[0];
    const float br = b_row_p[0];

    const int j0 = tid * 4;
    f32x4 c = *reinterpret_cast<const f32x4*>(&col_ws[b * K + j0]);
    f32x4 r = (f32x4){0.f, 0.f, 0.f, 0.f};
#pragma unroll
    for (int pblk = 0; pblk < 16; ++pblk)
        r += *reinterpret_cast<const f32x4*>(
            &rowpart[((size_t)(b * 16 + pblk)) * K + j0]);

    float acc = (c.x + bc) * (r.x + br)
              + (c.y + bc) * (r.y + br)
              + (c.z + bc) * (r.z + br)
              + (c.w + bc) * (r.w + br);
#pragma unroll
    for (int off = 32; off; off >>= 1) acc += __shfl_xor(acc, off);

    __shared__ float red[4];
    if (lane == 0) red[wave] = acc;
    __syncthreads();
    const float S = red[0] + red[1] + red[2] + red[3];

    f32x4 o = (f32x4){S, S, S, S};
    *reinterpret_cast<f32x4*>(&out[b * K + j0]) = o;
}

extern "C" void kernel_launch(void* const* d_in, const int* in_sizes, int n_in,
                              void* d_out, int out_size, void* d_ws, size_t ws_size,
                              hipStream_t stream) {
    const float* x     = (const float*)d_in[0];
    const float* w_col = (const float*)d_in[1];
    const float* b_col = (const float*)d_in[2];
    const float* w_row = (const float*)d_in[3];
    const float* b_row = (const float*)d_in[4];
    float* out = (float*)d_out;

    float* col_ws  = (float*)d_ws;               // NB*K floats
    float* rowpart = col_ws + (size_t)NB * K;    // NB*16*K floats

    rowcol_kernel<<<NB * 16, 256, 0, stream>>>(x, w_col, w_row, col_ws, rowpart);
    finalize_kernel<<<NB, 256, 0, stream>>>(col_ws, rowpart, b_col, b_row, out);
}

// Round 7
// 117.186 us; speedup vs baseline: 1.6497x; 1.6497x over previous
//
#include <hip/hip_runtime.h>
#include <hip/hip_bf16.h>

// Output[b,0,i] = S[b] for all i, where
//   S[b] = sum_j (row[b,j] + b_row) * (col[b,j] + b_col)
//   col[b,i] = sum_j x[b,i,j] * w_col[j]   (weighted row-dot)
//   row[b,j] = sum_i x[b,i,j] * w_row[i]   (weighted column-sum)
//
// R7 = R3 structure exactly (best known: 109 us), with PLAIN loads instead of
// nontemporal (A/B: NT hint may suppress Infinity-Cache retention of x;
// R4 counters showed LLC serves ~50% of x across graph replays even with NT).
// No __launch_bounds__ cap (R5/R6 proved the cap causes spill: demand ~148).

#define K 1024
#define NB 128

typedef float f32x4 __attribute__((ext_vector_type(4)));

__global__ __launch_bounds__(256) void
rowcol_kernel(const float* __restrict__ x,
              const float* __restrict__ w_col,
              const float* __restrict__ w_row,
              float* __restrict__ col_ws,     // [NB][K] raw (no bias)
              float* __restrict__ rowpart)    // [NB*16][K] per-block partials
{
    const int bid  = blockIdx.x;
    const int b    = bid >> 4;
    const int rb   = bid & 15;
    const int row0 = rb * 64;
    const int tid  = threadIdx.x;
    const int wave = tid >> 6;
    const int lane = tid & 63;

    const float* xb = x + (size_t)b * K * K;

    // Wave-uniform row base in SGPR so w_row[] reads scalarize to s_load.
    const int rbu = __builtin_amdgcn_readfirstlane(row0 + wave * 16);

    // Register-cache this lane's w_col fragment (reused by all 16 rows)
    f32x4 wc[4];
#pragma unroll
    for (int jt = 0; jt < 4; ++jt)
        wc[jt] = *reinterpret_cast<const f32x4*>(w_col + jt * 256 + lane * 4);

    // Per-lane column partials for row[b,j] (this wave's 16 rows)
    f32x4 p[4];
#pragma unroll
    for (int jt = 0; jt < 4; ++jt) p[jt] = (f32x4){0.f, 0.f, 0.f, 0.f};

    float cacc[16];

#pragma unroll
    for (int k = 0; k < 16; ++k) {
        const float wr = w_row[rbu + k];            // s_load, wave-uniform
        const float* xr = xb + (size_t)(rbu + k) * K;
        f32x4 xv0 = *reinterpret_cast<const f32x4*>(xr +   0 + lane * 4);
        f32x4 xv1 = *reinterpret_cast<const f32x4*>(xr + 256 + lane * 4);
        f32x4 xv2 = *reinterpret_cast<const f32x4*>(xr + 512 + lane * 4);
        f32x4 xv3 = *reinterpret_cast<const f32x4*>(xr + 768 + lane * 4);
        f32x4 c4;
        c4  = xv0 * wc[0];
        c4 += xv1 * wc[1];
        c4 += xv2 * wc[2];
        c4 += xv3 * wc[3];
        p[0] += xv0 * wr;
        p[1] += xv1 * wr;
        p[2] += xv2 * wr;
        p[3] += xv3 * wr;
        cacc[k] = (c4.x + c4.y) + (c4.z + c4.w);
    }

    // Multiplexed butterfly: 16 row-dots reduced across 64 lanes.
#pragma unroll
    for (int lvl = 0; lvl < 4; ++lvl) {
        const int s = 1 << lvl;
        const int n = 16 >> (lvl + 1);
#pragma unroll
        for (int m = 0; m < n; ++m) {
            float a  = cacc[2 * m]     + __shfl_xor(cacc[2 * m],     s);
            float bb = cacc[2 * m + 1] + __shfl_xor(cacc[2 * m + 1], s);
            cacc[m] = (lane & s) ? bb : a;
        }
    }
    float r = cacc[0];
    r += __shfl_xor(r, 16);
    r += __shfl_xor(r, 32);
    if (lane < 16) col_ws[b * K + rbu + lane] = r;   // one coalesced 64B store

    // Combine the 4 waves' column partials in LDS, write this block's partial
    __shared__ float rp[4][K];   // 16 KiB
#pragma unroll
    for (int jt = 0; jt < 4; ++jt)
        *reinterpret_cast<f32x4*>(&rp[wave][jt * 256 + lane * 4]) = p[jt];
    __syncthreads();

    const int j0 = tid * 4;   // thread tid owns columns j0..j0+3
    f32x4 s0 = *reinterpret_cast<const f32x4*>(&rp[0][j0]);
    f32x4 s1 = *reinterpret_cast<const f32x4*>(&rp[1][j0]);
    f32x4 s2 = *reinterpret_cast<const f32x4*>(&rp[2][j0]);
    f32x4 s3 = *reinterpret_cast<const f32x4*>(&rp[3][j0]);
    f32x4 s = (s0 + s1) + (s2 + s3);
    *reinterpret_cast<f32x4*>(&rowpart[(size_t)bid * K + j0]) = s;
}

__global__ __launch_bounds__(256) void
finalize_kernel(const float* __restrict__ col_ws,
                const float* __restrict__ rowpart,
                const float* __restrict__ b_col_p,
                const float* __restrict__ b_row_p,
                float* __restrict__ out)
{
    const int b    = blockIdx.x;
    const int tid  = threadIdx.x;
    const int wave = tid >> 6;
    const int lane = tid & 63;
    const float bc = b_col_p[0];
    const float br = b_row_p[0];

    const int j0 = tid * 4;
    f32x4 c = *reinterpret_cast<const f32x4*>(&col_ws[b * K + j0]);
    f32x4 r = (f32x4){0.f, 0.f, 0.f, 0.f};
#pragma unroll
    for (int pblk = 0; pblk < 16; ++pblk)
        r += *reinterpret_cast<const f32x4*>(
            &rowpart[((size_t)(b * 16 + pblk)) * K + j0]);

    float acc = (c.x + bc) * (r.x + br)
              + (c.y + bc) * (r.y + br)
              + (c.z + bc) * (r.z + br)
              + (c.w + bc) * (r.w + br);
#pragma unroll
    for (int off = 32; off; off >>= 1) acc += __shfl_xor(acc, off);

    __shared__ float red[4];
    if (lane == 0) red[wave] = acc;
    __syncthreads();
    const float S = red[0] + red[1] + red[2] + red[3];

    f32x4 o = (f32x4){S, S, S, S};
    *reinterpret_cast<f32x4*>(&out[b * K + j0]) = o;
}

extern "C" void kernel_launch(void* const* d_in, const int* in_sizes, int n_in,
                              void* d_out, int out_size, void* d_ws, size_t ws_size,
                              hipStream_t stream) {
    const float* x     = (const float*)d_in[0];
    const float* w_col = (const float*)d_in[1];
    const float* b_col = (const float*)d_in[2];
    const float* w_row = (const float*)d_in[3];
    const float* b_row = (const float*)d_in[4];
    float* out = (float*)d_out;

    float* col_ws  = (float*)d_ws;               // NB*K floats
    float* rowpart = col_ws + (size_t)NB * K;    // NB*16*K floats

    rowcol_kernel<<<NB * 16, 256, 0, stream>>>(x, w_col, w_row, col_ws, rowpart);
    finalize_kernel<<<NB, 256, 0, stream>>>(col_ws, rowpart, b_col, b_row, out);
}

// Round 8
// 100.118 us; speedup vs baseline: 1.9309x; 1.1705x over previous
//
#include <hip/hip_runtime.h>
#include <hip/hip_bf16.h>

// Output[b,0,i] = S[b] for all i, where
//   S[b] = sum_j (row[b,j] + b_row) * (col[b,j] + b_col)
//   col[b,i] = sum_j x[b,i,j] * w_col[j]   (weighted row-dot)
//   row[b,j] = sum_i x[b,i,j] * w_row[i]   (weighted column-sum)
//
// R8 = R3 (NT loads restored — R7 proved NT is +8us) + depth-1 software
// pipeline, NO __launch_bounds__ cap (R5/R6 proved the cap spills; pipeline
// alone adds ~32 VGPR -> ~180, same 3-waves/SIMD occupancy bin).

#define K 1024
#define NB 128

typedef float f32x4 __attribute__((ext_vector_type(4)));

__global__ __launch_bounds__(256) void
rowcol_kernel(const float* __restrict__ x,
              const float* __restrict__ w_col,
              const float* __restrict__ w_row,
              float* __restrict__ col_ws,     // [NB][K] raw (no bias)
              float* __restrict__ rowpart)    // [NB*16][K] per-block partials
{
    const int bid  = blockIdx.x;
    const int b    = bid >> 4;
    const int rb   = bid & 15;
    const int row0 = rb * 64;
    const int tid  = threadIdx.x;
    const int wave = tid >> 6;
    const int lane = tid & 63;

    const float* xb = x + (size_t)b * K * K;

    // Wave-uniform row base in SGPR so w_row[] reads scalarize to s_load.
    const int rbu = __builtin_amdgcn_readfirstlane(row0 + wave * 16);

    // Register-cache this lane's w_col fragment (reused by all 16 rows)
    f32x4 wc[4];
#pragma unroll
    for (int jt = 0; jt < 4; ++jt)
        wc[jt] = *reinterpret_cast<const f32x4*>(w_col + jt * 256 + lane * 4);

    // Per-lane column partials for row[b,j] (this wave's 16 rows)
    f32x4 p[4];
#pragma unroll
    for (int jt = 0; jt < 4; ++jt) p[jt] = (f32x4){0.f, 0.f, 0.f, 0.f};

    float cacc[16];

    // ---- depth-1 software-pipelined NT streaming loop ----
    const float* xr0 = xb + (size_t)rbu * K + lane * 4;
    f32x4 a0 = __builtin_nontemporal_load(reinterpret_cast<const f32x4*>(xr0 +   0));
    f32x4 a1 = __builtin_nontemporal_load(reinterpret_cast<const f32x4*>(xr0 + 256));
    f32x4 a2 = __builtin_nontemporal_load(reinterpret_cast<const f32x4*>(xr0 + 512));
    f32x4 a3 = __builtin_nontemporal_load(reinterpret_cast<const f32x4*>(xr0 + 768));

#pragma unroll
    for (int k = 0; k < 16; ++k) {
        f32x4 n0, n1, n2, n3;
        if (k < 15) {   // compile-time under full unroll
            const float* xn = xb + (size_t)(rbu + k + 1) * K + lane * 4;
            n0 = __builtin_nontemporal_load(reinterpret_cast<const f32x4*>(xn +   0));
            n1 = __builtin_nontemporal_load(reinterpret_cast<const f32x4*>(xn + 256));
            n2 = __builtin_nontemporal_load(reinterpret_cast<const f32x4*>(xn + 512));
            n3 = __builtin_nontemporal_load(reinterpret_cast<const f32x4*>(xn + 768));
        }
        const float wr = w_row[rbu + k];            // s_load, wave-uniform
        f32x4 c4;
        c4  = a0 * wc[0];
        c4 += a1 * wc[1];
        c4 += a2 * wc[2];
        c4 += a3 * wc[3];
        p[0] += a0 * wr;
        p[1] += a1 * wr;
        p[2] += a2 * wr;
        p[3] += a3 * wr;
        cacc[k] = (c4.x + c4.y) + (c4.z + c4.w);
        if (k < 15) { a0 = n0; a1 = n1; a2 = n2; a3 = n3; }
    }

    // Multiplexed butterfly: 16 row-dots reduced across 64 lanes.
#pragma unroll
    for (int lvl = 0; lvl < 4; ++lvl) {
        const int s = 1 << lvl;
        const int n = 16 >> (lvl + 1);
#pragma unroll
        for (int m = 0; m < n; ++m) {
            float a  = cacc[2 * m]     + __shfl_xor(cacc[2 * m],     s);
            float bb = cacc[2 * m + 1] + __shfl_xor(cacc[2 * m + 1], s);
            cacc[m] = (lane & s) ? bb : a;
        }
    }
    float r = cacc[0];
    r += __shfl_xor(r, 16);
    r += __shfl_xor(r, 32);
    if (lane < 16) col_ws[b * K + rbu + lane] = r;   // one coalesced 64B store

    // Combine the 4 waves' column partials in LDS, write this block's partial
    __shared__ float rp[4][K];   // 16 KiB
#pragma unroll
    for (int jt = 0; jt < 4; ++jt)
        *reinterpret_cast<f32x4*>(&rp[wave][jt * 256 + lane * 4]) = p[jt];
    __syncthreads();

    const int j0 = tid * 4;   // thread tid owns columns j0..j0+3
    f32x4 s0 = *reinterpret_cast<const f32x4*>(&rp[0][j0]);
    f32x4 s1 = *reinterpret_cast<const f32x4*>(&rp[1][j0]);
    f32x4 s2 = *reinterpret_cast<const f32x4*>(&rp[2][j0]);
    f32x4 s3 = *reinterpret_cast<const f32x4*>(&rp[3][j0]);
    f32x4 s = (s0 + s1) + (s2 + s3);
    *reinterpret_cast<f32x4*>(&rowpart[(size_t)bid * K + j0]) = s;
}

__global__ __launch_bounds__(256) void
finalize_kernel(const float* __restrict__ col_ws,
                const float* __restrict__ rowpart,
                const float* __restrict__ b_col_p,
                const float* __restrict__ b_row_p,
                float* __restrict__ out)
{
    const int b    = blockIdx.x;
    const int tid  = threadIdx.x;
    const int wave = tid >> 6;
    const int lane = tid & 63;
    const float bc = b_col_p[0];
    const float br = b_row_p[0];

    const int j0 = tid * 4;
    f32x4 c = *reinterpret_cast<const f32x4*>(&col_ws[b * K + j0]);
    f32x4 r = (f32x4){0.f, 0.f, 0.f, 0.f};
#pragma unroll
    for (int pblk = 0; pblk < 16; ++pblk)
        r += *reinterpret_cast<const f32x4*>(
            &rowpart[((size_t)(b * 16 + pblk)) * K + j0]);

    float acc = (c.x + bc) * (r.x + br)
              + (c.y + bc) * (r.y + br)
              + (c.z + bc) * (r.z + br)
              + (c.w + bc) * (r.w + br);
#pragma unroll
    for (int off = 32; off; off >>= 1) acc += __shfl_xor(acc, off);

    __shared__ float red[4];
    if (lane == 0) red[wave] = acc;
    __syncthreads();
    const float S = red[0] + red[1] + red[2] + red[3];

    f32x4 o = (f32x4){S, S, S, S};
    *reinterpret_cast<f32x4*>(&out[b * K + j0]) = o;
}

extern "C" void kernel_launch(void* const* d_in, const int* in_sizes, int n_in,
                              void* d_out, int out_size, void* d_ws, size_t ws_size,
                              hipStream_t stream) {
    const float* x     = (const float*)d_in[0];
    const float* w_col = (const float*)d_in[1];
    const float* b_col = (const float*)d_in[2];
    const float* w_row = (const float*)d_in[3];
    const float* b_row = (const float*)d_in[4];
    float* out = (float*)d_out;

    float* col_ws  = (float*)d_ws;               // NB*K floats
    float* rowpart = col_ws + (size_t)NB * K;    // NB*16*K floats

    rowcol_kernel<<<NB * 16, 256, 0, stream>>>(x, w_col, w_row, col_ws, rowpart);
    finalize_kernel<<<NB, 256, 0, stream>>>(col_ws, rowpart, b_col, b_row, out);
}

// Round 9
// 99.040 us; speedup vs baseline: 1.9519x; 1.0109x over previous
//
#include <hip/hip_runtime.h>
#include <hip/hip_bf16.h>

// Output[b,0,i] = S[b] for all i, where
//   S[b] = sum_j (row[b,j] + b_row) * (col[b,j] + b_col)
//   col[b,i] = sum_j x[b,i,j] * w_col[j]   (weighted row-dot)
//   row[b,j] = sum_i x[b,i,j] * w_row[i]   (weighted column-sum)
//
// R9 = R8 with the software pipeline deepened to 2 rows ahead (8-12 loads in
// flight per wave vs 4-8). NT loads (R7: +8us), no VGPR cap (R5/R6: cap
// spills). buf[k&1] is compile-time static under the full unroll.

#define K 1024
#define NB 128

typedef float f32x4 __attribute__((ext_vector_type(4)));

__global__ __launch_bounds__(256) void
rowcol_kernel(const float* __restrict__ x,
              const float* __restrict__ w_col,
              const float* __restrict__ w_row,
              float* __restrict__ col_ws,     // [NB][K] raw (no bias)
              float* __restrict__ rowpart)    // [NB*16][K] per-block partials
{
    const int bid  = blockIdx.x;
    const int b    = bid >> 4;
    const int rb   = bid & 15;
    const int row0 = rb * 64;
    const int tid  = threadIdx.x;
    const int wave = tid >> 6;
    const int lane = tid & 63;

    const float* xb = x + (size_t)b * K * K;

    // Wave-uniform row base in SGPR so w_row[] reads scalarize to s_load.
    const int rbu = __builtin_amdgcn_readfirstlane(row0 + wave * 16);

    // Register-cache this lane's w_col fragment (reused by all 16 rows)
    f32x4 wc[4];
#pragma unroll
    for (int jt = 0; jt < 4; ++jt)
        wc[jt] = *reinterpret_cast<const f32x4*>(w_col + jt * 256 + lane * 4);

    // Per-lane column partials for row[b,j] (this wave's 16 rows)
    f32x4 p[4];
#pragma unroll
    for (int jt = 0; jt < 4; ++jt) p[jt] = (f32x4){0.f, 0.f, 0.f, 0.f};

    float cacc[16];

    // ---- depth-2 software-pipelined NT streaming loop ----
    // buf[0] holds even rows, buf[1] odd rows; k&1 static under full unroll.
    f32x4 buf[2][4];
    {
        const float* xr0 = xb + (size_t)rbu * K + lane * 4;
        const float* xr1 = xb + (size_t)(rbu + 1) * K + lane * 4;
#pragma unroll
        for (int jt = 0; jt < 4; ++jt)
            buf[0][jt] = __builtin_nontemporal_load(
                reinterpret_cast<const f32x4*>(xr0 + jt * 256));
#pragma unroll
        for (int jt = 0; jt < 4; ++jt)
            buf[1][jt] = __builtin_nontemporal_load(
                reinterpret_cast<const f32x4*>(xr1 + jt * 256));
    }

#pragma unroll
    for (int k = 0; k < 16; ++k) {
        f32x4 n0, n1, n2, n3;
        if (k < 14) {   // issue row k+2's loads before consuming row k
            const float* xn = xb + (size_t)(rbu + k + 2) * K + lane * 4;
            n0 = __builtin_nontemporal_load(reinterpret_cast<const f32x4*>(xn +   0));
            n1 = __builtin_nontemporal_load(reinterpret_cast<const f32x4*>(xn + 256));
            n2 = __builtin_nontemporal_load(reinterpret_cast<const f32x4*>(xn + 512));
            n3 = __builtin_nontemporal_load(reinterpret_cast<const f32x4*>(xn + 768));
        }
        const float wr = w_row[rbu + k];            // s_load, wave-uniform
        f32x4 a0 = buf[k & 1][0], a1 = buf[k & 1][1];
        f32x4 a2 = buf[k & 1][2], a3 = buf[k & 1][3];
        f32x4 c4;
        c4  = a0 * wc[0];
        c4 += a1 * wc[1];
        c4 += a2 * wc[2];
        c4 += a3 * wc[3];
        p[0] += a0 * wr;
        p[1] += a1 * wr;
        p[2] += a2 * wr;
        p[3] += a3 * wr;
        cacc[k] = (c4.x + c4.y) + (c4.z + c4.w);
        if (k < 14) {
            buf[k & 1][0] = n0; buf[k & 1][1] = n1;
            buf[k & 1][2] = n2; buf[k & 1][3] = n3;
        }
    }

    // Multiplexed butterfly: 16 row-dots reduced across 64 lanes.
#pragma unroll
    for (int lvl = 0; lvl < 4; ++lvl) {
        const int s = 1 << lvl;
        const int n = 16 >> (lvl + 1);
#pragma unroll
        for (int m = 0; m < n; ++m) {
            float a  = cacc[2 * m]     + __shfl_xor(cacc[2 * m],     s);
            float bb = cacc[2 * m + 1] + __shfl_xor(cacc[2 * m + 1], s);
            cacc[m] = (lane & s) ? bb : a;
        }
    }
    float r = cacc[0];
    r += __shfl_xor(r, 16);
    r += __shfl_xor(r, 32);
    if (lane < 16) col_ws[b * K + rbu + lane] = r;   // one coalesced 64B store

    // Combine the 4 waves' column partials in LDS, write this block's partial
    __shared__ float rp[4][K];   // 16 KiB
#pragma unroll
    for (int jt = 0; jt < 4; ++jt)
        *reinterpret_cast<f32x4*>(&rp[wave][jt * 256 + lane * 4]) = p[jt];
    __syncthreads();

    const int j0 = tid * 4;   // thread tid owns columns j0..j0+3
    f32x4 s0 = *reinterpret_cast<const f32x4*>(&rp[0][j0]);
    f32x4 s1 = *reinterpret_cast<const f32x4*>(&rp[1][j0]);
    f32x4 s2 = *reinterpret_cast<const f32x4*>(&rp[2][j0]);
    f32x4 s3 = *reinterpret_cast<const f32x4*>(&rp[3][j0]);
    f32x4 s = (s0 + s1) + (s2 + s3);
    *reinterpret_cast<f32x4*>(&rowpart[(size_t)bid * K + j0]) = s;
}

__global__ __launch_bounds__(256) void
finalize_kernel(const float* __restrict__ col_ws,
                const float* __restrict__ rowpart,
                const float* __restrict__ b_col_p,
                const float* __restrict__ b_row_p,
                float* __restrict__ out)
{
    const int b    = blockIdx.x;
    const int tid  = threadIdx.x;
    const int wave = tid >> 6;
    const int lane = tid & 63;
    const float bc = b_col_p[0];
    const float br = b_row_p[0];

    const int j0 = tid * 4;
    f32x4 c = *reinterpret_cast<const f32x4*>(&col_ws[b * K + j0]);
    f32x4 r = (f32x4){0.f, 0.f, 0.f, 0.f};
#pragma unroll
    for (int pblk = 0; pblk < 16; ++pblk)
        r += *reinterpret_cast<const f32x4*>(
            &rowpart[((size_t)(b * 16 + pblk)) * K + j0]);

    float acc = (c.x + bc) * (r.x + br)
              + (c.y + bc) * (r.y + br)
              + (c.z + bc) * (r.z + br)
              + (c.w + bc) * (r.w + br);
#pragma unroll
    for (int off = 32; off; off >>= 1) acc += __shfl_xor(acc, off);

    __shared__ float red[4];
    if (lane == 0) red[wave] = acc;
    __syncthreads();
    const float S = red[0] + red[1] + red[2] + red[3];

    f32x4 o = (f32x4){S, S, S, S};
    *reinterpret_cast<f32x4*>(&out[b * K + j0]) = o;
}

extern "C" void kernel_launch(void* const* d_in, const int* in_sizes, int n_in,
                              void* d_out, int out_size, void* d_ws, size_t ws_size,
                              hipStream_t stream) {
    const float* x     = (const float*)d_in[0];
    const float* w_col = (const float*)d_in[1];
    const float* b_col = (const float*)d_in[2];
    const float* w_row = (const float*)d_in[3];
    const float* b_row = (const float*)d_in[4];
    float* out = (float*)d_out;

    float* col_ws  = (float*)d_ws;               // NB*K floats
    float* rowpart = col_ws + (size_t)NB * K;    // NB*16*K floats

    rowcol_kernel<<<NB * 16, 256, 0, stream>>>(x, w_col, w_row, col_ws, rowpart);
    finalize_kernel<<<NB, 256, 0, stream>>>(col_ws, rowpart, b_col, b_row, out);
}